// Round 3
// baseline (385.668 us; speedup 1.0000x reference)
//
#include <hip/hip_runtime.h>
#include <hip/hip_bf16.h>
#include <math.h>

typedef __bf16 bf16;
typedef __bf16 bf16x8 __attribute__((ext_vector_type(8)));
typedef float f32x4 __attribute__((ext_vector_type(4)));

#define TOK   16384      // 4*4096 tokens
#define D_    256        // feature dim per head
#define H_    8
#define HD    2048       // H_*D_
#define QKVN  6144       // 3*HD

// ---------------------------------------------------------------------------
// Dtype probe: if d_in tensors are fp32, reading them as bf16 pairs makes the
// EVEN elements the low mantissa bytes of fp32 words -> random exponents ->
// max abs explodes (or NaN). True bf16 N(0,1)-ish data stays < ~10.
// flag = 1 -> inputs are fp32; flag = 0 -> inputs are bf16.
// ---------------------------------------------------------------------------
__global__ void detect_dtype(const void* __restrict__ x, int* __restrict__ flag)
{
    int lane = threadIdx.x;
    const bf16* xb = (const bf16*)x;
    float m = 0.f;
    for (int i = lane; i < 4096; i += 64) {
        float v = fabsf((float)xb[2 * i]);     // even elements only
        if (!(v < 1e4f)) v = 1e30f;            // NaN or huge -> huge
        m = fmaxf(m, v);
    }
    for (int off = 32; off; off >>= 1) m = fmaxf(m, __shfl_xor(m, off, 64));
    if (lane == 0) *flag = (m > 1e4f) ? 1 : 0;
}

// ---------------------------------------------------------------------------
// Canonicalize a flat vector to bf16 (uniform branch on flag).
// ---------------------------------------------------------------------------
__global__ __launch_bounds__(256) void convert_vec(
    const void* __restrict__ src, bf16* __restrict__ dst, int n,
    const int* __restrict__ flag)
{
    int i = blockIdx.x * 256 + threadIdx.x;
    if (i >= n) return;
    float v = (*flag) ? ((const float*)src)[i] : (float)((const bf16*)src)[i];
    dst[i] = (bf16)v;
}

// ---------------------------------------------------------------------------
// Transpose + canonicalize: src (R x C, fp32 or bf16) -> dst (C x R, bf16)
// ---------------------------------------------------------------------------
__global__ __launch_bounds__(256) void transpose_cvt(
    const void* __restrict__ src, bf16* __restrict__ dst, int R, int C,
    const int* __restrict__ flag)
{
    __shared__ float tile[32][33];
    int f = *flag;
    int tc = blockIdx.x * 32, tr = blockIdx.y * 32;
    int lx = threadIdx.x & 31, ly = threadIdx.x >> 5;   // 32 x 8 threads
    for (int i = 0; i < 4; i++) {
        int r = ly + i * 8;
        size_t idx = (size_t)(tr + r) * C + tc + lx;
        tile[r][lx] = f ? ((const float*)src)[idx] : (float)((const bf16*)src)[idx];
    }
    __syncthreads();
    for (int i = 0; i < 4; i++) {
        int r = ly + i * 8;
        dst[(size_t)(tc + r) * R + tr + lx] = (bf16)tile[lx][r];
    }
}

// ---------------------------------------------------------------------------
// Kernel 1: qkv = x @ [Wq|Wk|Wv] + bias   (M=16384, K=256, N=6144)
// A = xb (row-major bf16), B = WT (6144 x 256, k-contiguous rows)
// 128x128 block tile, BK=64, 4 waves of 64x64. LDS 36 KB -> ~4 blocks/CU.
// ---------------------------------------------------------------------------
#define LD 72   // 64 + 8 pad; row stride 144 B -> 2-way bank alias (free)

__global__ __launch_bounds__(256) void proj_gemm(
    const bf16* __restrict__ X, const bf16* __restrict__ WT,
    const bf16* __restrict__ bqkv, bf16* __restrict__ qkv)
{
    __shared__ bf16 As[128 * LD];
    __shared__ bf16 Bs[128 * LD];
    int m0 = blockIdx.y * 128, n0 = blockIdx.x * 128;
    int tid = threadIdx.x;
    int wave = tid >> 6, lane = tid & 63;
    int wm = (wave >> 1) * 64, wn = (wave & 1) * 64;
    int lrow = lane & 15, lk = (lane >> 4) * 8;

    f32x4 acc[4][4] = {};
    for (int k0 = 0; k0 < D_; k0 += 64) {
        __syncthreads();
        for (int i = 0; i < 4; i++) {
            int seg = tid + i * 256;          // 0..1023 -> 128 rows x 8 chunks
            int row = seg >> 3, kc = (seg & 7) << 3;
            *(bf16x8*)&As[row * LD + kc] =
                *(const bf16x8*)&X[(size_t)(m0 + row) * D_ + k0 + kc];
            *(bf16x8*)&Bs[row * LD + kc] =
                *(const bf16x8*)&WT[(size_t)(n0 + row) * D_ + k0 + kc];
        }
        __syncthreads();
        for (int kk = 0; kk < 64; kk += 32) {
            bf16x8 af[4], bfv[4];
            for (int mt = 0; mt < 4; mt++)
                af[mt] = *(const bf16x8*)&As[(wm + mt * 16 + lrow) * LD + kk + lk];
            for (int nt = 0; nt < 4; nt++)
                bfv[nt] = *(const bf16x8*)&Bs[(wn + nt * 16 + lrow) * LD + kk + lk];
            for (int mt = 0; mt < 4; mt++)
                for (int nt = 0; nt < 4; nt++)
                    acc[mt][nt] = __builtin_amdgcn_mfma_f32_16x16x32_bf16(
                        af[mt], bfv[nt], acc[mt][nt], 0, 0, 0);
        }
    }

    int qd = lane >> 4;
    for (int nt = 0; nt < 4; nt++) {
        int col = n0 + wn + nt * 16 + lrow;
        float bias = (float)bqkv[col];
        for (int mt = 0; mt < 4; mt++) {
            int rbase = m0 + wm + mt * 16 + qd * 4;
            for (int r = 0; r < 4; r++)
                qkv[(size_t)(rbase + r) * QKVN + col] = (bf16)(acc[mt][nt][r] + bias);
        }
    }
}

// ---------------------------------------------------------------------------
// Kernel 2: per-token 8x8 head-vs-head attention. One wave per token quad.
// lane = (h,g): score dot, width-8 shuffle softmax, PV with VALU.
// Output overwrites the q slot of qkv in place.
// ---------------------------------------------------------------------------
__global__ __launch_bounds__(256) void attn(bf16* __restrict__ qkv)
{
    int wave = threadIdx.x >> 6, lane = threadIdx.x & 63;
    int tstart = blockIdx.x * 16 + wave * 4;
    int h = lane >> 3, g = lane & 7;

    for (int ti = 0; ti < 4; ti++) {
        int t = tstart + ti;
        const bf16* qp = qkv + (size_t)t * QKVN + h * D_;
        const bf16* kp = qkv + (size_t)t * QKVN + HD + g * D_;
        float s = 0.f;
        for (int c = 0; c < D_ / 8; c++) {
            bf16x8 a = *(const bf16x8*)(qp + c * 8);
            bf16x8 b = *(const bf16x8*)(kp + c * 8);
            for (int e = 0; e < 8; e++) s += (float)a[e] * (float)b[e];
        }
        s *= 0.0625f;  // d^-0.5
        float m = s;
        for (int off = 1; off < 8; off <<= 1) m = fmaxf(m, __shfl_xor(m, off, 8));
        float p = __expf(s - m);
        float sum = p;
        for (int off = 1; off < 8; off <<= 1) sum += __shfl_xor(sum, off, 8);
        p /= sum;

        float pv[8];
        for (int g2 = 0; g2 < 8; g2++) pv[g2] = __shfl(p, h * 8 + g2, 64);

        const bf16* vp = qkv + (size_t)t * QKVN + 2 * HD;
        bf16* op = qkv + (size_t)t * QKVN + h * D_ + g * 32;
        for (int u = 0; u < 4; u++) {
            float acc8[8] = {};
            for (int g2 = 0; g2 < 8; g2++) {
                bf16x8 v = *(const bf16x8*)(vp + g2 * D_ + g * 32 + u * 8);
                float pw = pv[g2];
                for (int e = 0; e < 8; e++) acc8[e] += pw * (float)v[e];
            }
            bf16x8 o;
            for (int e = 0; e < 8; e++) o[e] = (bf16)acc8[e];
            *(bf16x8*)(op + u * 8) = o;
        }
    }
}

// ---------------------------------------------------------------------------
// Kernel 3: final = attn_out @ Wo + bo   (M=16384, K=2048, N=256)
// A = q-slots of qkv (row stride QKVN), B = WoT (256 x 2048, k-contiguous)
// 64x128 block tile, BK=64. OUTPUT IS FP32 (reference's output dtype).
// ---------------------------------------------------------------------------
__global__ __launch_bounds__(256) void out_gemm(
    const bf16* __restrict__ qkv, const bf16* __restrict__ WoT,
    const bf16* __restrict__ bob, float* __restrict__ outp)
{
    __shared__ bf16 As[64 * LD];
    __shared__ bf16 Bs[128 * LD];
    int m0 = blockIdx.y * 64, n0 = blockIdx.x * 128;
    int tid = threadIdx.x;
    int wave = tid >> 6, lane = tid & 63;
    int wm = (wave >> 1) * 32, wn = (wave & 1) * 64;
    int lrow = lane & 15, lk = (lane >> 4) * 8;

    f32x4 acc[2][4] = {};
    for (int k0 = 0; k0 < HD; k0 += 64) {
        __syncthreads();
        for (int i = 0; i < 2; i++) {           // A: 64 rows x 64 k
            int seg = tid + i * 256;
            int row = seg >> 3, kc = (seg & 7) << 3;
            *(bf16x8*)&As[row * LD + kc] =
                *(const bf16x8*)&qkv[(size_t)(m0 + row) * QKVN + k0 + kc];
        }
        for (int i = 0; i < 4; i++) {           // B: 128 n-rows x 64 k
            int seg = tid + i * 256;
            int row = seg >> 3, kc = (seg & 7) << 3;
            *(bf16x8*)&Bs[row * LD + kc] =
                *(const bf16x8*)&WoT[(size_t)(n0 + row) * HD + k0 + kc];
        }
        __syncthreads();
        for (int kk = 0; kk < 64; kk += 32) {
            bf16x8 af[2], bfv[4];
            for (int mt = 0; mt < 2; mt++)
                af[mt] = *(const bf16x8*)&As[(wm + mt * 16 + lrow) * LD + kk + lk];
            for (int nt = 0; nt < 4; nt++)
                bfv[nt] = *(const bf16x8*)&Bs[(wn + nt * 16 + lrow) * LD + kk + lk];
            for (int mt = 0; mt < 2; mt++)
                for (int nt = 0; nt < 4; nt++)
                    acc[mt][nt] = __builtin_amdgcn_mfma_f32_16x16x32_bf16(
                        af[mt], bfv[nt], acc[mt][nt], 0, 0, 0);
        }
    }

    int qd = lane >> 4;
    for (int nt = 0; nt < 4; nt++) {
        int col = n0 + wn + nt * 16 + lrow;     // 0..255
        float bias = (float)bob[col];
        for (int mt = 0; mt < 2; mt++) {
            int rbase = m0 + wm + mt * 16 + qd * 4;
            for (int r = 0; r < 4; r++)
                outp[(size_t)(rbase + r) * D_ + col] = acc[mt][nt][r] + bias;
        }
    }
}

// ---------------------------------------------------------------------------
extern "C" void kernel_launch(void* const* d_in, const int* in_sizes, int n_in,
                              void* d_out, int out_size, void* d_ws, size_t ws_size,
                              hipStream_t stream)
{
    const void* x  = d_in[0];
    const void* Wq = d_in[1];
    const void* bq = d_in[2];
    const void* Wk = d_in[3];
    const void* bk = d_in[4];
    const void* Wv = d_in[5];
    const void* bv = d_in[6];
    const void* Wo = d_in[7];
    const void* bo = d_in[8];
    float* out = (float*)d_out;   // reference output dtype is fp32

    char* ws = (char*)d_ws;
    bf16* qkv  = (bf16*)ws;                          // 16384*6144*2 = 201326592
    bf16* WT   = (bf16*)(ws + 201326592);            // 6144*256*2   = 3145728
    bf16* WoT  = (bf16*)(ws + 204472320);            // 256*2048*2   = 1048576
    bf16* xb   = (bf16*)(ws + 205520896);            // 16384*256*2  = 8388608
    bf16* bqkv = (bf16*)(ws + 213909504);            // 6144*2       = 12288
    bf16* bob  = (bf16*)(ws + 213921792);            // 256*2        = 512
    int*  flag = (int*)(ws + 213922304);

    detect_dtype<<<1, 64, 0, stream>>>(x, flag);

    // canonicalize inputs to bf16
    convert_vec<<<16384, 256, 0, stream>>>(x, xb, TOK * D_, flag);
    convert_vec<<<8, 256, 0, stream>>>(bq, bqkv,          HD, flag);
    convert_vec<<<8, 256, 0, stream>>>(bk, bqkv + HD,     HD, flag);
    convert_vec<<<8, 256, 0, stream>>>(bv, bqkv + 2 * HD, HD, flag);
    convert_vec<<<1, 256, 0, stream>>>(bo, bob,           D_, flag);

    // weight transposes (k-contiguous B operands), bf16 canonical
    transpose_cvt<<<dim3(64, 8), 256, 0, stream>>>(Wq, WT,              256, 2048, flag);
    transpose_cvt<<<dim3(64, 8), 256, 0, stream>>>(Wk, WT + 2048 * 256, 256, 2048, flag);
    transpose_cvt<<<dim3(64, 8), 256, 0, stream>>>(Wv, WT + 4096 * 256, 256, 2048, flag);
    transpose_cvt<<<dim3(8, 64), 256, 0, stream>>>(Wo, WoT,            2048, 256, flag);

    proj_gemm<<<dim3(48, 128), 256, 0, stream>>>(xb, WT, bqkv, qkv);
    attn<<<1024, 256, 0, stream>>>(qkv);
    out_gemm<<<dim3(2, 256), 256, 0, stream>>>(qkv, WoT, bob, out);
}

// Round 4
// 325.674 us; speedup vs baseline: 1.1842x; 1.1842x over previous
//
#include <hip/hip_runtime.h>
#include <hip/hip_bf16.h>
#include <math.h>

typedef __bf16 bf16;
typedef __bf16 bf16x4 __attribute__((ext_vector_type(4)));
typedef __bf16 bf16x8 __attribute__((ext_vector_type(8)));
typedef float f32x4 __attribute__((ext_vector_type(4)));
typedef unsigned int u32;
typedef u32 __attribute__((address_space(1))) gu32;
typedef u32 __attribute__((address_space(3))) lu32;

#define TOK   16384
#define D_    256
#define HD    2048
#define QKVN  6144

// async global->LDS, 16 B per lane; LDS dest = base + lane*16
#define GLDS16(g, l) __builtin_amdgcn_global_load_lds((gu32*)(g), (lu32*)(l), 16, 0, 0)

// ---------------------------------------------------------------------------
// Dtype probe (fp32 vs bf16 inputs): reading fp32 as bf16 pairs makes even
// elements random-exponent garbage -> max explodes. flag=1 -> fp32.
// ---------------------------------------------------------------------------
__global__ void detect_dtype(const void* __restrict__ x, int* __restrict__ flag)
{
    int lane = threadIdx.x;
    const bf16* xb = (const bf16*)x;
    float m = 0.f;
    for (int i = lane; i < 4096; i += 64) {
        float v = fabsf((float)xb[2 * i]);
        if (!(v < 1e4f)) v = 1e30f;
        m = fmaxf(m, v);
    }
    for (int off = 32; off; off >>= 1) m = fmaxf(m, __shfl_xor(m, off, 64));
    if (lane == 0) *flag = (m > 1e4f) ? 1 : 0;
}

__global__ __launch_bounds__(256) void convert_vec(
    const void* __restrict__ src, bf16* __restrict__ dst, int n,
    const int* __restrict__ flag)
{
    int i = blockIdx.x * 256 + threadIdx.x;
    if (i >= n) return;
    float v = (*flag) ? ((const float*)src)[i] : (float)((const bf16*)src)[i];
    dst[i] = (bf16)v;
}

__global__ __launch_bounds__(256) void transpose_cvt(
    const void* __restrict__ src, bf16* __restrict__ dst, int R, int C,
    const int* __restrict__ flag)
{
    __shared__ float tile[32][33];
    int f = *flag;
    int tc = blockIdx.x * 32, tr = blockIdx.y * 32;
    int lx = threadIdx.x & 31, ly = threadIdx.x >> 5;
    for (int i = 0; i < 4; i++) {
        int r = ly + i * 8;
        size_t idx = (size_t)(tr + r) * C + tc + lx;
        tile[r][lx] = f ? ((const float*)src)[idx] : (float)((const bf16*)src)[idx];
    }
    __syncthreads();
    for (int i = 0; i < 4; i++) {
        int r = ly + i * 8;
        dst[(size_t)(tc + r) * R + tr + lx] = (bf16)tile[lx][r];
    }
}

// ---------------------------------------------------------------------------
// Kernel 1: qkv = x @ [Wq|Wk|Wv] + bias   (M=16384, K=256, N=6144)
// m97-style: 128x128 tile, BK=64, global_load_lds width 16, unpadded LDS.
// mfma(bfv, af): lane&15 = token row (m), acc regs = 4 consecutive N-cols.
// ---------------------------------------------------------------------------
__global__ __launch_bounds__(256) void proj_gemm(
    const bf16* __restrict__ X, const bf16* __restrict__ WT,
    const bf16* __restrict__ bqkv, bf16* __restrict__ qkv)
{
    __shared__ bf16 As[128 * 64];
    __shared__ bf16 Bs[128 * 64];
    int m0 = blockIdx.y * 128, n0 = blockIdx.x * 128;
    int tid = threadIdx.x, wave = tid >> 6, lane = tid & 63;
    int wm = (wave >> 1) * 64, wn = (wave & 1) * 64;
    int mrow = lane & 15, quad = lane >> 4;

    f32x4 acc[4][4] = {};
    for (int k0 = 0; k0 < D_; k0 += 64) {
        __syncthreads();
        for (int i = 0; i < 4; i++) {
            int rbase = wave * 32 + i * 8;
            int row = rbase + (lane >> 3), col = (lane & 7) * 8;
            GLDS16(&X[(size_t)(m0 + row) * D_ + k0 + col], &As[rbase * 64]);
            GLDS16(&WT[(size_t)(n0 + row) * D_ + k0 + col], &Bs[rbase * 64]);
        }
        __syncthreads();
        for (int kk = 0; kk < 64; kk += 32) {
            bf16x8 af[4], bfv[4];
            for (int mt = 0; mt < 4; mt++)
                af[mt] = *(const bf16x8*)&As[(wm + mt * 16 + mrow) * 64 + kk + quad * 8];
            for (int nt = 0; nt < 4; nt++)
                bfv[nt] = *(const bf16x8*)&Bs[(wn + nt * 16 + mrow) * 64 + kk + quad * 8];
            for (int mt = 0; mt < 4; mt++)
                for (int nt = 0; nt < 4; nt++)
                    acc[mt][nt] = __builtin_amdgcn_mfma_f32_16x16x32_bf16(
                        bfv[nt], af[mt], acc[mt][nt], 0, 0, 0);
        }
    }

    for (int mt = 0; mt < 4; mt++) {
        int row = m0 + wm + mt * 16 + mrow;
        for (int nt = 0; nt < 4; nt++) {
            int col = n0 + wn + nt * 16 + quad * 4;
            bf16x4 bb = *(const bf16x4*)&bqkv[col];
            bf16x4 o;
            for (int r = 0; r < 4; r++) o[r] = (bf16)(acc[mt][nt][r] + (float)bb[r]);
            *(bf16x4*)&qkv[(size_t)row * QKVN + col] = o;
        }
    }
}

// ---------------------------------------------------------------------------
// Kernel 2: per-token 8x8 attention, per-wave LDS staging via global_load_lds.
// k rows XOR-swizzled (chunk c stored at c^g) so 8-lane score-read groups span
// all 32 banks. Lane (h,g) owns out chunks g+8m -> conflict-free v reads and
// out writes. Output staged in LDS, stored as 4x1KB contiguous wave-writes.
// ---------------------------------------------------------------------------
__global__ __launch_bounds__(256) void attn(bf16* __restrict__ qkv)
{
    __shared__ bf16 sh[4][8192];   // per wave: 24*256 qkv + 2048 out
    int wave = threadIdx.x >> 6, lane = threadIdx.x & 63;
    bf16* sq = sh[wave];
    bf16* sout = sh[wave] + 6144;
    int h = lane >> 3, g = lane & 7;
    int t0 = blockIdx.x * 16 + wave * 4;

    for (int ti = 0; ti < 4; ti++) {
        int t = t0 + ti;
        bf16* base = qkv + (size_t)t * QKVN;
        // stage 24 rows x 256 (q rows 0-7, k 8-15, v 16-23); k rows permuted
        for (int i = 0; i < 12; i++) {
            int s = i * 64 + lane;
            int row = s >> 5, cs = s & 31;
            int gc = (row >= 8 && row < 16) ? (cs ^ (row & 7)) : cs;
            GLDS16(base + row * 256 + gc * 8, (char*)sq + i * 1024);
        }
        __syncthreads();

        // scores: lane (h,g) = q[h] . k[g]
        const bf16* qrow = sq + h * 256;
        const bf16* krow = sq + (8 + g) * 256;
        float s = 0.f;
        for (int c = 0; c < 32; c++) {
            bf16x8 a = *(const bf16x8*)&qrow[c * 8];
            bf16x8 b = *(const bf16x8*)&krow[(c ^ g) * 8];
            for (int e = 0; e < 8; e++) s += (float)a[e] * (float)b[e];
        }
        s *= 0.0625f;
        float m = s;
        for (int off = 1; off < 8; off <<= 1) m = fmaxf(m, __shfl_xor(m, off, 8));
        float p = __expf(s - m);
        float sum = p;
        for (int off = 1; off < 8; off <<= 1) sum += __shfl_xor(sum, off, 8);
        p /= sum;

        float pv[8];
        for (int g2 = 0; g2 < 8; g2++) pv[g2] = __shfl(p, h * 8 + g2, 64);

        // PV: lane (h,g) accumulates out[h] chunks g+8m (m=0..3)
        float acc[4][8] = {};
        for (int g2 = 0; g2 < 8; g2++) {
            float pw = pv[g2];
            const bf16* vrow = sq + (16 + g2) * 256;
            for (int mm = 0; mm < 4; mm++) {
                bf16x8 v = *(const bf16x8*)&vrow[(g + 8 * mm) * 8];
                for (int e = 0; e < 8; e++) acc[mm][e] += pw * (float)v[e];
            }
        }
        for (int mm = 0; mm < 4; mm++) {
            bf16x8 o;
            for (int e = 0; e < 8; e++) o[e] = (bf16)acc[mm][e];
            *(bf16x8*)&sout[h * 256 + (g + 8 * mm) * 8] = o;
        }
        __syncthreads();

        // coalesced store to q slot
        for (int i = 0; i < 4; i++) {
            int sidx = i * 64 + lane;
            *(bf16x8*)&base[sidx * 8] = *(const bf16x8*)&sout[sidx * 8];
        }
    }
}

// ---------------------------------------------------------------------------
// Kernel 3: out = attn_out @ Wo + bo   (M=16384, K=2048, N=256), fp32 out.
// 128x64 tile, BK=64, glds staging, swapped-operand mfma, f32x4 stores.
// ---------------------------------------------------------------------------
__global__ __launch_bounds__(256) void out_gemm(
    const bf16* __restrict__ qkv, const bf16* __restrict__ WoT,
    const bf16* __restrict__ bob, float* __restrict__ outp)
{
    __shared__ bf16 As[128 * 64];
    __shared__ bf16 Bs[64 * 64];
    int m0 = blockIdx.y * 128, n0 = blockIdx.x * 64;
    int tid = threadIdx.x, wave = tid >> 6, lane = tid & 63;
    int wm = (wave >> 1) * 64, wn = (wave & 1) * 32;
    int mrow = lane & 15, quad = lane >> 4;

    f32x4 acc[4][2] = {};
    for (int k0 = 0; k0 < HD; k0 += 64) {
        __syncthreads();
        for (int i = 0; i < 4; i++) {
            int rbase = wave * 32 + i * 8;
            int row = rbase + (lane >> 3), col = (lane & 7) * 8;
            GLDS16(&qkv[(size_t)(m0 + row) * QKVN + k0 + col], &As[rbase * 64]);
        }
        for (int i = 0; i < 2; i++) {
            int rbase = wave * 16 + i * 8;
            int row = rbase + (lane >> 3), col = (lane & 7) * 8;
            GLDS16(&WoT[(size_t)(n0 + row) * HD + k0 + col], &Bs[rbase * 64]);
        }
        __syncthreads();
        for (int kk = 0; kk < 64; kk += 32) {
            bf16x8 af[4], bfv[2];
            for (int mt = 0; mt < 4; mt++)
                af[mt] = *(const bf16x8*)&As[(wm + mt * 16 + mrow) * 64 + kk + quad * 8];
            for (int nt = 0; nt < 2; nt++)
                bfv[nt] = *(const bf16x8*)&Bs[(wn + nt * 16 + mrow) * 64 + kk + quad * 8];
            for (int mt = 0; mt < 4; mt++)
                for (int nt = 0; nt < 2; nt++)
                    acc[mt][nt] = __builtin_amdgcn_mfma_f32_16x16x32_bf16(
                        bfv[nt], af[mt], acc[mt][nt], 0, 0, 0);
        }
    }

    for (int mt = 0; mt < 4; mt++) {
        int row = m0 + wm + mt * 16 + mrow;
        for (int nt = 0; nt < 2; nt++) {
            int col = n0 + wn + nt * 16 + quad * 4;
            bf16x4 bb = *(const bf16x4*)&bob[col];
            f32x4 o;
            for (int r = 0; r < 4; r++) o[r] = acc[mt][nt][r] + (float)bb[r];
            *(f32x4*)&outp[(size_t)row * D_ + col] = o;
        }
    }
}

// ---------------------------------------------------------------------------
extern "C" void kernel_launch(void* const* d_in, const int* in_sizes, int n_in,
                              void* d_out, int out_size, void* d_ws, size_t ws_size,
                              hipStream_t stream)
{
    const void* x  = d_in[0];
    const void* Wq = d_in[1];
    const void* bq = d_in[2];
    const void* Wk = d_in[3];
    const void* bk = d_in[4];
    const void* Wv = d_in[5];
    const void* bv = d_in[6];
    const void* Wo = d_in[7];
    const void* bo = d_in[8];
    float* out = (float*)d_out;

    char* ws = (char*)d_ws;
    bf16* qkv  = (bf16*)ws;                          // 201326592 B
    bf16* WT   = (bf16*)(ws + 201326592);            // 3145728 B
    bf16* WoT  = (bf16*)(ws + 204472320);            // 1048576 B
    bf16* xb   = (bf16*)(ws + 205520896);            // 8388608 B
    bf16* bqkv = (bf16*)(ws + 213909504);            // 12288 B
    bf16* bob  = (bf16*)(ws + 213921792);            // 512 B
    int*  flag = (int*)(ws + 213922304);

    detect_dtype<<<1, 64, 0, stream>>>(x, flag);

    convert_vec<<<16384, 256, 0, stream>>>(x, xb, TOK * D_, flag);
    convert_vec<<<8, 256, 0, stream>>>(bq, bqkv,          HD, flag);
    convert_vec<<<8, 256, 0, stream>>>(bk, bqkv + HD,     HD, flag);
    convert_vec<<<8, 256, 0, stream>>>(bv, bqkv + 2 * HD, HD, flag);
    convert_vec<<<1, 256, 0, stream>>>(bo, bob,           D_, flag);

    transpose_cvt<<<dim3(64, 8), 256, 0, stream>>>(Wq, WT,              256, 2048, flag);
    transpose_cvt<<<dim3(64, 8), 256, 0, stream>>>(Wk, WT + 2048 * 256, 256, 2048, flag);
    transpose_cvt<<<dim3(64, 8), 256, 0, stream>>>(Wv, WT + 4096 * 256, 256, 2048, flag);
    transpose_cvt<<<dim3(8, 64), 256, 0, stream>>>(Wo, WoT,            2048, 256, flag);

    proj_gemm<<<dim3(48, 128), 256, 0, stream>>>(xb, WT, bqkv, qkv);
    attn<<<1024, 256, 0, stream>>>(qkv);
    out_gemm<<<dim3(4, 128), 256, 0, stream>>>(qkv, WoT, bob, out);
}

// Round 5
// 311.124 us; speedup vs baseline: 1.2396x; 1.0468x over previous
//
#include <hip/hip_runtime.h>
#include <hip/hip_bf16.h>
#include <math.h>

typedef __bf16 bf16;
typedef __bf16 bf16x4 __attribute__((ext_vector_type(4)));
typedef __bf16 bf16x8 __attribute__((ext_vector_type(8)));
typedef float f32x4 __attribute__((ext_vector_type(4)));
typedef unsigned int u32;
typedef u32 __attribute__((address_space(1))) gu32;
typedef u32 __attribute__((address_space(3))) lu32;

#define TOK   16384
#define D_    256
#define HD    2048
#define QKVN  6144

// async global->LDS, 16 B/lane; LDS dest = uniform base + lane*16
#define GLDS16(g, l) __builtin_amdgcn_global_load_lds((gu32*)(g), (lu32*)(l), 16, 0, 0)
// wait vmcnt(0) only (expcnt=7, lgkmcnt=15 -> no wait): wave-private glds drain
#define WAIT_VM0() __builtin_amdgcn_s_waitcnt(0x0f70)

// ---------------------------------------------------------------------------
// Dtype probe: fp32-as-bf16 even elements are mantissa garbage -> max explodes.
// ---------------------------------------------------------------------------
__global__ void detect_dtype(const void* __restrict__ x, int* __restrict__ flag)
{
    int lane = threadIdx.x;
    const bf16* xb = (const bf16*)x;
    float m = 0.f;
    for (int i = lane; i < 4096; i += 64) {
        float v = fabsf((float)xb[2 * i]);
        if (!(v < 1e4f)) v = 1e30f;
        m = fmaxf(m, v);
    }
    for (int off = 32; off; off >>= 1) m = fmaxf(m, __shfl_xor(m, off, 64));
    if (lane == 0) *flag = (m > 1e4f) ? 1 : 0;
}

__global__ __launch_bounds__(256) void convert_vec(
    const void* __restrict__ src, bf16* __restrict__ dst, int n,
    const int* __restrict__ flag)
{
    int i = blockIdx.x * 256 + threadIdx.x;
    if (i >= n) return;
    float v = (*flag) ? ((const float*)src)[i] : (float)((const bf16*)src)[i];
    dst[i] = (bf16)v;
}

__global__ __launch_bounds__(256) void transpose_cvt(
    const void* __restrict__ src, bf16* __restrict__ dst, int R, int C,
    const int* __restrict__ flag)
{
    __shared__ float tile[32][33];
    int f = *flag;
    int tc = blockIdx.x * 32, tr = blockIdx.y * 32;
    int lx = threadIdx.x & 31, ly = threadIdx.x >> 5;
    for (int i = 0; i < 4; i++) {
        int r = ly + i * 8;
        size_t idx = (size_t)(tr + r) * C + tc + lx;
        tile[r][lx] = f ? ((const float*)src)[idx] : (float)((const bf16*)src)[idx];
    }
    __syncthreads();
    for (int i = 0; i < 4; i++) {
        int r = ly + i * 8;
        dst[(size_t)(tc + r) * R + tr + lx] = (bf16)tile[lx][r];
    }
}

// ---------------------------------------------------------------------------
// Kernel 1: qkv = x @ [Wq|Wk|Wv] + bias   (M=16384, K=256, N=6144)
// 256x128 block tile, BK=64, glds staging, XOR-swizzled LDS (slot = c^(row&7))
// -> conflict-free ds_read_b128. Per-wave 128x64, acc[8][4].
// ---------------------------------------------------------------------------
__global__ __launch_bounds__(256, 2) void proj_gemm(
    const bf16* __restrict__ X, const bf16* __restrict__ WT,
    const bf16* __restrict__ bqkv, bf16* __restrict__ qkv)
{
    __shared__ bf16 As[256 * 64];   // 32 KB
    __shared__ bf16 Bs[128 * 64];   // 16 KB
    int m0 = blockIdx.y * 256, n0 = blockIdx.x * 128;
    int tid = threadIdx.x, wave = tid >> 6, lane = tid & 63;
    int wm = (wave >> 1) * 128, wn = (wave & 1) * 64;
    int mrow = lane & 15, quad = lane >> 4;
    int lrow8 = lane >> 3, lslot = lane & 7;

    f32x4 acc[8][4] = {};
    for (int k0 = 0; k0 < D_; k0 += 64) {
        __syncthreads();
        for (int i = 0; i < 8; i++) {           // A: wave stages 64 rows
            int rbase = wave * 64 + i * 8;
            int row = rbase + lrow8;
            int gc = lslot ^ (row & 7);
            GLDS16(&X[(size_t)(m0 + row) * D_ + k0 + gc * 8], &As[rbase * 64]);
        }
        for (int i = 0; i < 4; i++) {           // B: wave stages 32 rows
            int rbase = wave * 32 + i * 8;
            int row = rbase + lrow8;
            int gc = lslot ^ (row & 7);
            GLDS16(&WT[(size_t)(n0 + row) * D_ + k0 + gc * 8], &Bs[rbase * 64]);
        }
        __syncthreads();
        for (int kk = 0; kk < 64; kk += 32) {
            int slot = (((kk >> 3) + quad) ^ (mrow & 7)) * 8;
            bf16x8 af[8], bfv[4];
            for (int mt = 0; mt < 8; mt++)
                af[mt] = *(const bf16x8*)&As[(wm + mt * 16 + mrow) * 64 + slot];
            for (int nt = 0; nt < 4; nt++)
                bfv[nt] = *(const bf16x8*)&Bs[(wn + nt * 16 + mrow) * 64 + slot];
            for (int mt = 0; mt < 8; mt++)
                for (int nt = 0; nt < 4; nt++)
                    acc[mt][nt] = __builtin_amdgcn_mfma_f32_16x16x32_bf16(
                        bfv[nt], af[mt], acc[mt][nt], 0, 0, 0);
        }
    }

    for (int mt = 0; mt < 8; mt++) {
        int row = m0 + wm + mt * 16 + mrow;
        for (int nt = 0; nt < 4; nt++) {
            int col = n0 + wn + nt * 16 + quad * 4;
            bf16x4 bb = *(const bf16x4*)&bqkv[col];
            bf16x4 o;
            for (int r = 0; r < 4; r++) o[r] = (bf16)(acc[mt][nt][r] + (float)bb[r]);
            *(bf16x4*)&qkv[(size_t)row * QKVN + col] = o;
        }
    }
}

// ---------------------------------------------------------------------------
// Kernel 2: per-token 8x8 attention. Wave-private LDS staging (glds) with
// s_waitcnt vmcnt(0) only -- NO block barriers. Unified row swizzle
// (slot = c ^ (row&7)) -> conflict-free q/k/v reads. Direct coalesced stores.
// ---------------------------------------------------------------------------
__global__ __launch_bounds__(256) void attn(bf16* __restrict__ qkv)
{
    __shared__ bf16 sh[4][6144];   // per wave: 24 rows x 256
    int wave = threadIdx.x >> 6, lane = threadIdx.x & 63;
    bf16* sq = sh[wave];
    int h = lane >> 3, g = lane & 7;
    int t0 = blockIdx.x * 16 + wave * 4;

    for (int ti = 0; ti < 4; ti++) {
        int t = t0 + ti;
        bf16* base = qkv + (size_t)t * QKVN;
        // stage 24 rows x 256 (q 0-7, k 8-15, v 16-23), chunk c at slot c^(row&7)
        for (int i = 0; i < 12; i++) {
            int s = i * 64 + lane;
            int row = s >> 5, cs = s & 31;
            int gc = cs ^ (row & 7);
            GLDS16(base + row * 256 + gc * 8, (char*)sq + i * 1024);
        }
        WAIT_VM0();

        // scores: lane (h,g) = q[h] . k[g]
        const bf16* qrow = sq + h * 256;
        const bf16* krow = sq + (8 + g) * 256;
        float s = 0.f;
        for (int c = 0; c < 32; c++) {
            bf16x8 a = *(const bf16x8*)&qrow[(c ^ h) * 8];
            bf16x8 b = *(const bf16x8*)&krow[(c ^ g) * 8];
            for (int e = 0; e < 8; e++) s += (float)a[e] * (float)b[e];
        }
        s *= 0.0625f;
        float m = s;
        for (int off = 1; off < 8; off <<= 1) m = fmaxf(m, __shfl_xor(m, off, 8));
        float p = __expf(s - m);
        float sum = p;
        for (int off = 1; off < 8; off <<= 1) sum += __shfl_xor(sum, off, 8);
        p /= sum;

        float pv[8];
        for (int g2 = 0; g2 < 8; g2++) pv[g2] = __shfl(p, h * 8 + g2, 64);

        // PV: lane (h,g) accumulates out[h] chunks g+8m
        float acc[4][8] = {};
        for (int g2 = 0; g2 < 8; g2++) {
            float pw = pv[g2];
            const bf16* vrow = sq + (16 + g2) * 256;
            for (int mm = 0; mm < 4; mm++) {
                bf16x8 v = *(const bf16x8*)&vrow[((g ^ g2) + 8 * mm) * 8];
                for (int e = 0; e < 8; e++) acc[mm][e] += pw * (float)v[e];
            }
        }
        // direct store: 8-lane groups cover 128 B contiguous per head row
        for (int mm = 0; mm < 4; mm++) {
            bf16x8 o;
            for (int e = 0; e < 8; e++) o[e] = (bf16)acc[mm][e];
            *(bf16x8*)&base[h * 256 + (g + 8 * mm) * 8] = o;
        }
    }
}

// ---------------------------------------------------------------------------
// Kernel 3: out = attn_out @ Wo + bo  (M=16384, K=2048, N=256), fp32 out.
// 128x64 tile, BK=64, glds staging, XOR-swizzled LDS, f32x4 stores.
// ---------------------------------------------------------------------------
__global__ __launch_bounds__(256) void out_gemm(
    const bf16* __restrict__ qkv, const bf16* __restrict__ WoT,
    const bf16* __restrict__ bob, float* __restrict__ outp)
{
    __shared__ bf16 As[128 * 64];
    __shared__ bf16 Bs[64 * 64];
    int m0 = blockIdx.y * 128, n0 = blockIdx.x * 64;
    int tid = threadIdx.x, wave = tid >> 6, lane = tid & 63;
    int wm = (wave >> 1) * 64, wn = (wave & 1) * 32;
    int mrow = lane & 15, quad = lane >> 4;
    int lrow8 = lane >> 3, lslot = lane & 7;

    f32x4 acc[4][2] = {};
    for (int k0 = 0; k0 < HD; k0 += 64) {
        __syncthreads();
        for (int i = 0; i < 4; i++) {
            int rbase = wave * 32 + i * 8;
            int row = rbase + lrow8;
            int gc = lslot ^ (row & 7);
            GLDS16(&qkv[(size_t)(m0 + row) * QKVN + k0 + gc * 8], &As[rbase * 64]);
        }
        for (int i = 0; i < 2; i++) {
            int rbase = wave * 16 + i * 8;
            int row = rbase + lrow8;
            int gc = lslot ^ (row & 7);
            GLDS16(&WoT[(size_t)(n0 + row) * HD + k0 + gc * 8], &Bs[rbase * 64]);
        }
        __syncthreads();
        for (int kk = 0; kk < 64; kk += 32) {
            int slot = (((kk >> 3) + quad) ^ (mrow & 7)) * 8;
            bf16x8 af[4], bfv[2];
            for (int mt = 0; mt < 4; mt++)
                af[mt] = *(const bf16x8*)&As[(wm + mt * 16 + mrow) * 64 + slot];
            for (int nt = 0; nt < 2; nt++)
                bfv[nt] = *(const bf16x8*)&Bs[(wn + nt * 16 + mrow) * 64 + slot];
            for (int mt = 0; mt < 4; mt++)
                for (int nt = 0; nt < 2; nt++)
                    acc[mt][nt] = __builtin_amdgcn_mfma_f32_16x16x32_bf16(
                        bfv[nt], af[mt], acc[mt][nt], 0, 0, 0);
        }
    }

    for (int mt = 0; mt < 4; mt++) {
        int row = m0 + wm + mt * 16 + mrow;
        for (int nt = 0; nt < 2; nt++) {
            int col = n0 + wn + nt * 16 + quad * 4;
            bf16x4 bb = *(const bf16x4*)&bob[col];
            f32x4 o;
            for (int r = 0; r < 4; r++) o[r] = acc[mt][nt][r] + (float)bb[r];
            *(f32x4*)&outp[(size_t)row * D_ + col] = o;
        }
    }
}

// ---------------------------------------------------------------------------
extern "C" void kernel_launch(void* const* d_in, const int* in_sizes, int n_in,
                              void* d_out, int out_size, void* d_ws, size_t ws_size,
                              hipStream_t stream)
{
    const void* x  = d_in[0];
    const void* Wq = d_in[1];
    const void* bq = d_in[2];
    const void* Wk = d_in[3];
    const void* bk = d_in[4];
    const void* Wv = d_in[5];
    const void* bv = d_in[6];
    const void* Wo = d_in[7];
    const void* bo = d_in[8];
    float* out = (float*)d_out;

    char* ws = (char*)d_ws;
    bf16* qkv  = (bf16*)ws;                          // 201326592 B
    bf16* WT   = (bf16*)(ws + 201326592);            // 3145728 B
    bf16* WoT  = (bf16*)(ws + 204472320);            // 1048576 B
    bf16* xb   = (bf16*)(ws + 205520896);            // 8388608 B
    bf16* bqkv = (bf16*)(ws + 213909504);            // 12288 B
    bf16* bob  = (bf16*)(ws + 213921792);            // 512 B
    int*  flag = (int*)(ws + 213922304);

    detect_dtype<<<1, 64, 0, stream>>>(x, flag);

    convert_vec<<<16384, 256, 0, stream>>>(x, xb, TOK * D_, flag);
    convert_vec<<<8, 256, 0, stream>>>(bq, bqkv,          HD, flag);
    convert_vec<<<8, 256, 0, stream>>>(bk, bqkv + HD,     HD, flag);
    convert_vec<<<8, 256, 0, stream>>>(bv, bqkv + 2 * HD, HD, flag);
    convert_vec<<<1, 256, 0, stream>>>(bo, bob,           D_, flag);

    transpose_cvt<<<dim3(64, 8), 256, 0, stream>>>(Wq, WT,              256, 2048, flag);
    transpose_cvt<<<dim3(64, 8), 256, 0, stream>>>(Wk, WT + 2048 * 256, 256, 2048, flag);
    transpose_cvt<<<dim3(64, 8), 256, 0, stream>>>(Wv, WT + 4096 * 256, 256, 2048, flag);
    transpose_cvt<<<dim3(8, 64), 256, 0, stream>>>(Wo, WoT,            2048, 256, flag);

    proj_gemm<<<dim3(48, 64), 256, 0, stream>>>(xb, WT, bqkv, qkv);
    attn<<<1024, 256, 0, stream>>>(qkv);
    out_gemm<<<dim3(4, 128), 256, 0, stream>>>(qkv, WoT, bob, out);
}

// Round 6
// 294.247 us; speedup vs baseline: 1.3107x; 1.0574x over previous
//
#include <hip/hip_runtime.h>
#include <hip/hip_bf16.h>
#include <math.h>

typedef __bf16 bf16;
typedef __bf16 bf16x4 __attribute__((ext_vector_type(4)));
typedef __bf16 bf16x8 __attribute__((ext_vector_type(8)));
typedef float f32x4 __attribute__((ext_vector_type(4)));
typedef unsigned int u32;
typedef u32 __attribute__((address_space(1))) gu32;
typedef u32 __attribute__((address_space(3))) lu32;

#define TOK   16384
#define D_    256
#define HD    2048
#define QKVN  6144

// async global->LDS, 16 B/lane; LDS dest = uniform base + lane*16
#define GLDS16(g, l) __builtin_amdgcn_global_load_lds((gu32*)(g), (lu32*)(l), 16, 0, 0)
// wait vmcnt(0) only (expcnt=7, lgkmcnt=15): wave-private glds drain
#define WAIT_VM0() __builtin_amdgcn_s_waitcnt(0x0f70)

// ---------------------------------------------------------------------------
// Dtype probe: fp32-as-bf16 even elements are mantissa garbage -> max explodes.
// ---------------------------------------------------------------------------
__global__ void detect_dtype(const void* __restrict__ x, int* __restrict__ flag)
{
    int lane = threadIdx.x;
    const bf16* xb = (const bf16*)x;
    float m = 0.f;
    for (int i = lane; i < 4096; i += 64) {
        float v = fabsf((float)xb[2 * i]);
        if (!(v < 1e4f)) v = 1e30f;
        m = fmaxf(m, v);
    }
    for (int off = 32; off; off >>= 1) m = fmaxf(m, __shfl_xor(m, off, 64));
    if (lane == 0) *flag = (m > 1e4f) ? 1 : 0;
}

// vectorized x convert: 4 elems/thread
__global__ __launch_bounds__(256) void convert_x(
    const void* __restrict__ src, bf16* __restrict__ dst,
    const int* __restrict__ flag)
{
    int i = blockIdx.x * 256 + threadIdx.x;      // i < TOK*D_/4
    bf16x4 o;
    if (*flag) {
        f32x4 v = ((const f32x4*)src)[i];
        for (int e = 0; e < 4; e++) o[e] = (bf16)v[e];
    } else {
        o = ((const bf16x4*)src)[i];
    }
    ((bf16x4*)dst)[i] = o;
}

// all four bias vectors in one launch: bq|bk|bv -> bqkv[0..6143], bo -> bob
__global__ __launch_bounds__(256) void fuse_bias(
    const void* __restrict__ bq, const void* __restrict__ bk,
    const void* __restrict__ bv, const void* __restrict__ bo,
    bf16* __restrict__ bqkv, bf16* __restrict__ bob,
    const int* __restrict__ flag)
{
    int i = blockIdx.x * 256 + threadIdx.x;
    if (i >= 6400) return;
    const void* src; bf16* dst; int off;
    if (i < 2048)      { src = bq; dst = bqkv;        off = i; }
    else if (i < 4096) { src = bk; dst = bqkv + 2048; off = i - 2048; }
    else if (i < 6144) { src = bv; dst = bqkv + 4096; off = i - 4096; }
    else               { src = bo; dst = bob;         off = i - 6144; }
    float v = (*flag) ? ((const float*)src)[off] : (float)((const bf16*)src)[off];
    dst[off] = (bf16)v;
}

// transpose+convert, 3 weights in one launch (z selects); src R=256 x C=2048
__global__ __launch_bounds__(256) void transpose_cvt3(
    const void* __restrict__ Wq, const void* __restrict__ Wk,
    const void* __restrict__ Wv, bf16* __restrict__ WT,
    const int* __restrict__ flag)
{
    __shared__ float tile[32][33];
    int z = blockIdx.z;
    const void* src = (z == 0) ? Wq : (z == 1) ? Wk : Wv;
    bf16* dst = WT + (size_t)z * 2048 * 256;
    int f = *flag;
    int R = 256, C = 2048;
    int tc = blockIdx.x * 32, tr = blockIdx.y * 32;
    int lx = threadIdx.x & 31, ly = threadIdx.x >> 5;
    for (int i = 0; i < 4; i++) {
        int r = ly + i * 8;
        size_t idx = (size_t)(tr + r) * C + tc + lx;
        tile[r][lx] = f ? ((const float*)src)[idx] : (float)((const bf16*)src)[idx];
    }
    __syncthreads();
    for (int i = 0; i < 4; i++) {
        int r = ly + i * 8;
        dst[(size_t)(tc + r) * R + tr + lx] = (bf16)tile[lx][r];
    }
}

__global__ __launch_bounds__(256) void transpose_cvt(
    const void* __restrict__ src, bf16* __restrict__ dst, int R, int C,
    const int* __restrict__ flag)
{
    __shared__ float tile[32][33];
    int f = *flag;
    int tc = blockIdx.x * 32, tr = blockIdx.y * 32;
    int lx = threadIdx.x & 31, ly = threadIdx.x >> 5;
    for (int i = 0; i < 4; i++) {
        int r = ly + i * 8;
        size_t idx = (size_t)(tr + r) * C + tc + lx;
        tile[r][lx] = f ? ((const float*)src)[idx] : (float)((const bf16*)src)[idx];
    }
    __syncthreads();
    for (int i = 0; i < 4; i++) {
        int r = ly + i * 8;
        dst[(size_t)(tc + r) * R + tr + lx] = (bf16)tile[lx][r];
    }
}

// ---------------------------------------------------------------------------
// Kernel 1: qkv = x @ [Wq|Wk|Wv] + bias   (M=16384, K=256, N=6144)
// m97 config: 128x128 tile, BK=64, glds, XOR-swizzle -> 0 conflicts.
// acc[4][4] (64 AGPR) + ~80 VGPR -> 3 waves/SIMD, LDS 32 KB.
// ---------------------------------------------------------------------------
__global__ __launch_bounds__(256) void proj_gemm(
    const bf16* __restrict__ X, const bf16* __restrict__ WT,
    const bf16* __restrict__ bqkv, bf16* __restrict__ qkv)
{
    __shared__ bf16 As[128 * 64];   // 16 KB
    __shared__ bf16 Bs[128 * 64];   // 16 KB
    int m0 = blockIdx.y * 128, n0 = blockIdx.x * 128;
    int tid = threadIdx.x, wave = tid >> 6, lane = tid & 63;
    int wm = (wave >> 1) * 64, wn = (wave & 1) * 64;
    int mrow = lane & 15, quad = lane >> 4;
    int lrow8 = lane >> 3, lslot = lane & 7;

    f32x4 acc[4][4] = {};
    for (int k0 = 0; k0 < D_; k0 += 64) {
        __syncthreads();
        for (int i = 0; i < 4; i++) {
            int rbase = wave * 32 + i * 8;
            int row = rbase + lrow8;
            int gc = lslot ^ (row & 7);
            GLDS16(&X[(size_t)(m0 + row) * D_ + k0 + gc * 8], &As[rbase * 64]);
            GLDS16(&WT[(size_t)(n0 + row) * D_ + k0 + gc * 8], &Bs[rbase * 64]);
        }
        __syncthreads();
        for (int kk = 0; kk < 64; kk += 32) {
            int slot = (((kk >> 3) + quad) ^ (mrow & 7)) * 8;
            bf16x8 af[4], bfv[4];
            for (int mt = 0; mt < 4; mt++)
                af[mt] = *(const bf16x8*)&As[(wm + mt * 16 + mrow) * 64 + slot];
            for (int nt = 0; nt < 4; nt++)
                bfv[nt] = *(const bf16x8*)&Bs[(wn + nt * 16 + mrow) * 64 + slot];
            for (int mt = 0; mt < 4; mt++)
                for (int nt = 0; nt < 4; nt++)
                    acc[mt][nt] = __builtin_amdgcn_mfma_f32_16x16x32_bf16(
                        bfv[nt], af[mt], acc[mt][nt], 0, 0, 0);
        }
    }

    for (int mt = 0; mt < 4; mt++) {
        int row = m0 + wm + mt * 16 + mrow;
        for (int nt = 0; nt < 4; nt++) {
            int col = n0 + wn + nt * 16 + quad * 4;
            bf16x4 bb = *(const bf16x4*)&bqkv[col];
            bf16x4 o;
            for (int r = 0; r < 4; r++) o[r] = (bf16)(acc[mt][nt][r] + (float)bb[r]);
            *(bf16x4*)&qkv[(size_t)row * QKVN + col] = o;
        }
    }
}

// ---------------------------------------------------------------------------
// Kernel 2: per-token 8x8 attention (unchanged from round 5 — passed, and
// next profile will expose its true cost once proj drops below it).
// ---------------------------------------------------------------------------
__global__ __launch_bounds__(256) void attn(bf16* __restrict__ qkv)
{
    __shared__ bf16 sh[4][6144];
    int wave = threadIdx.x >> 6, lane = threadIdx.x & 63;
    bf16* sq = sh[wave];
    int h = lane >> 3, g = lane & 7;
    int t0 = blockIdx.x * 16 + wave * 4;

    for (int ti = 0; ti < 4; ti++) {
        int t = t0 + ti;
        bf16* base = qkv + (size_t)t * QKVN;
        for (int i = 0; i < 12; i++) {
            int s = i * 64 + lane;
            int row = s >> 5, cs = s & 31;
            int gc = cs ^ (row & 7);
            GLDS16(base + row * 256 + gc * 8, (char*)sq + i * 1024);
        }
        WAIT_VM0();

        const bf16* qrow = sq + h * 256;
        const bf16* krow = sq + (8 + g) * 256;
        float s = 0.f;
        for (int c = 0; c < 32; c++) {
            bf16x8 a = *(const bf16x8*)&qrow[(c ^ h) * 8];
            bf16x8 b = *(const bf16x8*)&krow[(c ^ g) * 8];
            for (int e = 0; e < 8; e++) s += (float)a[e] * (float)b[e];
        }
        s *= 0.0625f;
        float m = s;
        for (int off = 1; off < 8; off <<= 1) m = fmaxf(m, __shfl_xor(m, off, 8));
        float p = __expf(s - m);
        float sum = p;
        for (int off = 1; off < 8; off <<= 1) sum += __shfl_xor(sum, off, 8);
        p /= sum;

        float pv[8];
        for (int g2 = 0; g2 < 8; g2++) pv[g2] = __shfl(p, h * 8 + g2, 64);

        float acc[4][8] = {};
        for (int g2 = 0; g2 < 8; g2++) {
            float pw = pv[g2];
            const bf16* vrow = sq + (16 + g2) * 256;
            for (int mm = 0; mm < 4; mm++) {
                bf16x8 v = *(const bf16x8*)&vrow[((g ^ g2) + 8 * mm) * 8];
                for (int e = 0; e < 8; e++) acc[mm][e] += pw * (float)v[e];
            }
        }
        for (int mm = 0; mm < 4; mm++) {
            bf16x8 o;
            for (int e = 0; e < 8; e++) o[e] = (bf16)acc[mm][e];
            *(bf16x8*)&base[h * 256 + (g + 8 * mm) * 8] = o;
        }
    }
}

// ---------------------------------------------------------------------------
// Kernel 3: out = attn_out @ Wo + bo  (M=16384, K=2048, N=256), fp32 out.
// 128x64 tile, BK=128 (16 K-iters, 2x barrier amortization), 48 KB LDS,
// XOR-swizzled (chunk c of 16 at slot c^(row&7)).
// ---------------------------------------------------------------------------
__global__ __launch_bounds__(256) void out_gemm(
    const bf16* __restrict__ qkv, const bf16* __restrict__ WoT,
    const bf16* __restrict__ bob, float* __restrict__ outp)
{
    __shared__ bf16 As[128 * 128];  // 32 KB
    __shared__ bf16 Bs[64 * 128];   // 16 KB
    int m0 = blockIdx.y * 128, n0 = blockIdx.x * 64;
    int tid = threadIdx.x, wave = tid >> 6, lane = tid & 63;
    int wm = (wave >> 1) * 64, wn = (wave & 1) * 32;
    int mrow = lane & 15, quad = lane >> 4;
    int lrow16 = lane >> 4, lslot16 = lane & 15;   // 16 chunks of 16 B per row

    f32x4 acc[4][2] = {};
    for (int k0 = 0; k0 < HD; k0 += 128) {
        __syncthreads();
        for (int i = 0; i < 8; i++) {            // A: wave stages 32 rows
            int rbase = wave * 32 + i * 4;
            int row = rbase + lrow16;
            int gc = lslot16 ^ (row & 7);
            GLDS16(&qkv[(size_t)(m0 + row) * QKVN + k0 + gc * 8], &As[rbase * 128]);
        }
        for (int i = 0; i < 4; i++) {            // B: wave stages 16 rows
            int rbase = wave * 16 + i * 4;
            int row = rbase + lrow16;
            int gc = lslot16 ^ (row & 7);
            GLDS16(&WoT[(size_t)(n0 + row) * HD + k0 + gc * 8], &Bs[rbase * 128]);
        }
        __syncthreads();
        for (int kk = 0; kk < 128; kk += 32) {
            int slot = (((kk >> 3) + quad) ^ (mrow & 7)) * 8;
            bf16x8 af[4], bfv[2];
            for (int mt = 0; mt < 4; mt++)
                af[mt] = *(const bf16x8*)&As[(wm + mt * 16 + mrow) * 128 + slot];
            for (int nt = 0; nt < 2; nt++)
                bfv[nt] = *(const bf16x8*)&Bs[(wn + nt * 16 + mrow) * 128 + slot];
            for (int mt = 0; mt < 4; mt++)
                for (int nt = 0; nt < 2; nt++)
                    acc[mt][nt] = __builtin_amdgcn_mfma_f32_16x16x32_bf16(
                        bfv[nt], af[mt], acc[mt][nt], 0, 0, 0);
        }
    }

    for (int mt = 0; mt < 4; mt++) {
        int row = m0 + wm + mt * 16 + mrow;
        for (int nt = 0; nt < 2; nt++) {
            int col = n0 + wn + nt * 16 + quad * 4;
            bf16x4 bb = *(const bf16x4*)&bob[col];
            f32x4 o;
            for (int r = 0; r < 4; r++) o[r] = acc[mt][nt][r] + (float)bb[r];
            *(f32x4*)&outp[(size_t)row * D_ + col] = o;
        }
    }
}

// ---------------------------------------------------------------------------
extern "C" void kernel_launch(void* const* d_in, const int* in_sizes, int n_in,
                              void* d_out, int out_size, void* d_ws, size_t ws_size,
                              hipStream_t stream)
{
    const void* x  = d_in[0];
    const void* Wq = d_in[1];
    const void* bq = d_in[2];
    const void* Wk = d_in[3];
    const void* bk = d_in[4];
    const void* Wv = d_in[5];
    const void* bv = d_in[6];
    const void* Wo = d_in[7];
    const void* bo = d_in[8];
    float* out = (float*)d_out;

    char* ws = (char*)d_ws;
    bf16* qkv  = (bf16*)ws;                          // 201326592 B
    bf16* WT   = (bf16*)(ws + 201326592);            // 3145728 B
    bf16* WoT  = (bf16*)(ws + 204472320);            // 1048576 B
    bf16* xb   = (bf16*)(ws + 205520896);            // 8388608 B
    bf16* bqkv = (bf16*)(ws + 213909504);            // 12288 B
    bf16* bob  = (bf16*)(ws + 213921792);            // 512 B
    int*  flag = (int*)(ws + 213922304);

    detect_dtype<<<1, 64, 0, stream>>>(x, flag);

    convert_x<<<4096, 256, 0, stream>>>(x, xb, flag);          // TOK*D_/4 / 256
    fuse_bias<<<25, 256, 0, stream>>>(bq, bk, bv, bo, bqkv, bob, flag);
    transpose_cvt3<<<dim3(64, 8, 3), 256, 0, stream>>>(Wq, Wk, Wv, WT, flag);
    transpose_cvt<<<dim3(8, 64), 256, 0, stream>>>(Wo, WoT, 2048, 256, flag);

    proj_gemm<<<dim3(48, 128), 256, 0, stream>>>(xb, WT, bqkv, qkv);
    attn<<<1024, 256, 0, stream>>>(qkv);
    out_gemm<<<dim3(4, 128), 256, 0, stream>>>(qkv, WoT, bob, out);
}